// Round 5
// baseline (1403.529 us; speedup 1.0000x reference)
//
#include <hip/hip_runtime.h>

#define BN_EPS 1e-5f

typedef unsigned long long u64;

// ---------------- shared-memory union ----------------
struct FpsSm {
  uint4    slotD[2][4];   // per wave: {dist_bits, ~j, x_bits, y_bits}, parity-buffered
  unsigned slotZ[2][4];   // z_bits
  unsigned tags[2][4];    // iteration tag, written LAST (DS pipe is in-order per wave)
  float    sel[3 * 1024]; // selected points, flushed once at end
};
struct FeatSm {
  float W1s[256];        // folded layer-1 weights: [c][4] = a*w0,a*w1,a*w2, be-a*mean
  float h1s[128][68];    // padded rows (68 floats = 272B, 16B aligned)
  float stat[4][64][8];  // per-wave partial stats
};
union __align__(16) SMem { FpsSm fps; FeatSm feat; };

// ---------------- fast wave-wide max (DPP) ----------------
#if __has_builtin(__builtin_amdgcn_update_dpp) && __has_builtin(__builtin_amdgcn_readlane)
template<int CTRL>
__device__ __forceinline__ float dppmax(float x) {
  const int t = __builtin_amdgcn_update_dpp(0, __float_as_int(x), CTRL, 0xf, 0xf, true);
  return fmaxf(x, __int_as_float(t));
}
__device__ __forceinline__ float wave_max_f32(float x) {
  x = dppmax<0x111>(x);  // row_shr:1
  x = dppmax<0x112>(x);  // row_shr:2
  x = dppmax<0x114>(x);  // row_shr:4
  x = dppmax<0x118>(x);  // row_shr:8
  x = dppmax<0x142>(x);  // row_bcast15
  x = dppmax<0x143>(x);  // row_bcast31
  return __int_as_float(__builtin_amdgcn_readlane(__float_as_int(x), 63));
}
#else
__device__ __forceinline__ float wave_max_f32(float x) {
  for (int off = 32; off; off >>= 1) x = fmaxf(x, __shfl_xor(x, off));
  return x;
}
#endif

__device__ __forceinline__ int rdlane_i(int v, int l) {
  return __builtin_amdgcn_readlane(v, l);
}
__device__ __forceinline__ float rdlane_f(float v, int l) {
  return __int_as_float(__builtin_amdgcn_readlane(__float_as_int(v), l));
}

// ---------------- FPS: 4 waves, barrier-free tagged-slot exchange ----------------
template<int NPTS>
__device__ void fps_body(const float* __restrict__ pts, float* __restrict__ ptsNext,
                         float* __restrict__ momNext, SMem* sm) {
  constexpr int R = NPTS / 256;
  constexpr int M = NPTS / 2;
  const int b    = blockIdx.x;
  const int tid  = threadIdx.x;
  const int lane = tid & 63;
  const int w    = tid >> 6;
  const float* p0 = pts + (size_t)b * NPTS * 3;
  float* sel = sm->fps.sel;

  if (tid < 8) ((unsigned*)sm->fps.tags)[tid] = 0u;   // tags start at 0; it starts at 1

  float px[R], py[R], pz[R], mind[R];
#pragma unroll
  for (int i = 0; i < R; i++) {
    const int j = tid + 256 * i;
    px[i] = p0[3*j]; py[i] = p0[3*j+1]; pz[i] = p0[3*j+2];
  }

  float sx = p0[0], sy = p0[1], sz = p0[2];
  // moments of selected points (for next level's layer-1 BN stats)
  float m0 = sx, m1 = sy, m2 = sz;
  float m3 = sx*sx, m4 = sy*sy, m5 = sz*sz, m6 = sx*sy, m7 = sx*sz, m8 = sy*sz;
  if (tid == 0) { sel[0] = sx; sel[1] = sy; sel[2] = sz; }

  // per-lane best: value, global index, coords (carried via cndmask)
  float bv = -1.0f, bx = 0.f, by = 0.f, bz = 0.f; int bj = 0;
#pragma unroll
  for (int i = 0; i < R; i++) {
    const float dx = px[i]-sx, dy = py[i]-sy, dz = pz[i]-sz;
    const float d = __fadd_rn(__fadd_rn(__fmul_rn(dx,dx), __fmul_rn(dy,dy)), __fmul_rn(dz,dz));
    mind[i] = d;
    if (d > bv) { bv = d; bj = tid + 256*i; bx = px[i]; by = py[i]; bz = pz[i]; }
  }

  __syncthreads();   // covers tags init; the ONLY barrier until the final flush

  for (int it = 1; it < M; ++it) {
    // --- wave-level: value max via DPP, then pick owner lane ---
    const float smax = wave_max_f32(bv);
    unsigned long long mk = __ballot(bv == smax);
    if (__popcll(mk) > 1) {            // exact ties (rare): first (lowest) index wins
      int jj = (bv == smax) ? bj : 0x7fffffff;
#pragma unroll
      for (int off = 32; off; off >>= 1) jj = min(jj, __shfl_xor(jj, off));
      mk = __ballot((bv == smax) && (bj == jj));
    }
    const int winl = (int)(__ffsll(mk) - 1);
    const unsigned wj = (unsigned)rdlane_i(bj, winl);
    const float wx = rdlane_f(bx, winl);
    const float wy = rdlane_f(by, winl);
    const float wz = rdlane_f(bz, winl);

    // --- publish wave candidate: data first, tag last (DS FIFO per wave) ---
    const int par = it & 1;
    if (lane == 0) {
      sm->fps.slotD[par][w] = make_uint4(__float_as_uint(smax), ~wj,
                                         __float_as_uint(wx), __float_as_uint(wy));
      sm->fps.slotZ[par][w] = __float_as_uint(wz);
      asm volatile("" ::: "memory");
      *(volatile unsigned*)&sm->fps.tags[par][w] = (unsigned)it;
    }

    // --- spin until all 4 wave tags reach this iteration (no barrier) ---
    {
      const unsigned itu = (unsigned)it;
      volatile unsigned* tg = &sm->fps.tags[par][0];
      unsigned t0, t1, t2, t3;
      do { t0 = tg[0]; t1 = tg[1]; t2 = tg[2]; t3 = tg[3]; }
      while ((t0 != itu) | (t1 != itu) | (t2 != itu) | (t3 != itu));
      asm volatile("" ::: "memory");
    }

    // --- combine 4 candidates (64-bit key = dist_bits:~j, max = farthest, ties->lowest j) ---
    const uint4 k0 = sm->fps.slotD[par][0], k1 = sm->fps.slotD[par][1];
    const uint4 k2 = sm->fps.slotD[par][2], k3 = sm->fps.slotD[par][3];
    const float z0 = __uint_as_float(sm->fps.slotZ[par][0]);
    const float z1 = __uint_as_float(sm->fps.slotZ[par][1]);
    const float z2 = __uint_as_float(sm->fps.slotZ[par][2]);
    const float z3 = __uint_as_float(sm->fps.slotZ[par][3]);
    const u64 K0 = ((u64)k0.x << 32) | k0.y;
    const u64 K1 = ((u64)k1.x << 32) | k1.y;
    const u64 K2 = ((u64)k2.x << 32) | k2.y;
    const u64 K3 = ((u64)k3.x << 32) | k3.y;
    const bool a01 = K1 > K0, a23 = K3 > K2;
    const u64 Ka = a01 ? K1 : K0, Kb = a23 ? K3 : K2;
    const uint4 kA = a01 ? k1 : k0, kB = a23 ? k3 : k2;
    const float zA = a01 ? z1 : z0, zB = a23 ? z3 : z2;
    const bool ab = Kb > Ka;
    const uint4 kW = ab ? kB : kA;
    sx = __uint_as_float(kW.z); sy = __uint_as_float(kW.w); sz = ab ? zB : zA;

    if (tid == 0) { sel[3*it] = sx; sel[3*it+1] = sy; sel[3*it+2] = sz; }
    m0 += sx; m1 += sy; m2 += sz;
    m3 = fmaf(sx,sx,m3); m4 = fmaf(sy,sy,m4); m5 = fmaf(sz,sz,m5);
    m6 = fmaf(sx,sy,m6); m7 = fmaf(sx,sz,m7); m8 = fmaf(sy,sz,m8);

    // --- distance update + per-lane argmax scan ---
    bv = -1.0f; bj = 0;
#pragma unroll
    for (int i = 0; i < R; i++) {
      const float dx = px[i]-sx, dy = py[i]-sy, dz = pz[i]-sz;
      const float d = __fadd_rn(__fadd_rn(__fmul_rn(dx,dx), __fmul_rn(dy,dy)), __fmul_rn(dz,dz));
      const float mv = fminf(mind[i], d);
      mind[i] = mv;
      if (mv > bv) { bv = mv; bj = tid + 256*i; bx = px[i]; by = py[i]; bz = pz[i]; }
    }
  }
  if (tid == 0) {
    float* o = momNext + b * 9;
    o[0]=m0; o[1]=m1; o[2]=m2; o[3]=m3; o[4]=m4; o[5]=m5; o[6]=m6; o[7]=m7; o[8]=m8;
  }
  // bulk coalesced flush of selected points (LDS -> global), once
  __syncthreads();
  float* o = ptsNext + (size_t)b * M * 3;
#pragma unroll 4
  for (int e = tid; e < 3 * M; e += 256) o[e] = sel[e];
}

// ---------------- feature pass: h1=relu(BN1(x@w1)), y2=h1@w2; stats+extremes ----------------
template<int NPTS>
__device__ void featB_body(const float* __restrict__ pts, const float* __restrict__ W1f,
                           const float* __restrict__ w2, float* __restrict__ partialsB,
                           int fbid, SMem* sm) {
  const int tid  = threadIdx.x;
  const int lane = tid & 63;
  const int w    = tid >> 6;
  constexpr int BPB = NPTS / 256;       // blocks per batch
  const int b = fbid / BPB;
  const size_t pbase = (size_t)b * NPTS + (size_t)(fbid % BPB) * 256;

  float* W1s = sm->feat.W1s;
  W1s[tid < 256 ? tid : 0] = W1f[tid < 256 ? tid : 0];
  __syncthreads();

  // per-lane layer-2 weight columns: channel `lane` and `lane+64`
  float wA[64], wB[64];
#pragma unroll
  for (int k = 0; k < 64; k++) { wA[k] = w2[k*128 + lane]; wB[k] = w2[k*128 + 64 + lane]; }

  float sA=0.f, qA=0.f, sB=0.f, qB=0.f;
  float mxA=-1e30f, mnA=1e30f, mxB=-1e30f, mnB=1e30f;

  for (int r = 0; r < 2; r++) {
    __syncthreads();                     // protect h1s overwrite vs previous round's reads
    if (tid < 128) {                     // phase A: compute h1 for 128 points
      const float* pp = pts + (pbase + (size_t)r*128 + tid) * 3;
      const float x = pp[0], y = pp[1], z = pp[2];
#pragma unroll
      for (int k = 0; k < 64; k += 4) {
        float4 hv;
        { const float4 wf = *reinterpret_cast<const float4*>(&W1s[4*(k  )]);
          hv.x = fmaxf(0.f, fmaf(x,wf.x, fmaf(y,wf.y, fmaf(z,wf.z, wf.w)))); }
        { const float4 wf = *reinterpret_cast<const float4*>(&W1s[4*(k+1)]);
          hv.y = fmaxf(0.f, fmaf(x,wf.x, fmaf(y,wf.y, fmaf(z,wf.z, wf.w)))); }
        { const float4 wf = *reinterpret_cast<const float4*>(&W1s[4*(k+2)]);
          hv.z = fmaxf(0.f, fmaf(x,wf.x, fmaf(y,wf.y, fmaf(z,wf.z, wf.w)))); }
        { const float4 wf = *reinterpret_cast<const float4*>(&W1s[4*(k+3)]);
          hv.w = fmaxf(0.f, fmaf(x,wf.x, fmaf(y,wf.y, fmaf(z,wf.z, wf.w)))); }
        *reinterpret_cast<float4*>(&sm->feat.h1s[tid][k]) = hv;
      }
    }
    __syncthreads();
    // phase B: wave w consumes rows [w*32, w*32+32)
    const int row0 = w * 32;
    for (int p = row0; p < row0 + 32; ++p) {
      float ya = 0.f, yb = 0.f;
#pragma unroll
      for (int k = 0; k < 64; k += 4) {
        const float4 hv = *reinterpret_cast<const float4*>(&sm->feat.h1s[p][k]);
        ya = fmaf(hv.x, wA[k  ], ya);  yb = fmaf(hv.x, wB[k  ], yb);
        ya = fmaf(hv.y, wA[k+1], ya);  yb = fmaf(hv.y, wB[k+1], yb);
        ya = fmaf(hv.z, wA[k+2], ya);  yb = fmaf(hv.z, wB[k+2], yb);
        ya = fmaf(hv.w, wA[k+3], ya);  yb = fmaf(hv.w, wB[k+3], yb);
      }
      sA += ya; qA = fmaf(ya,ya,qA); mxA = fmaxf(mxA,ya); mnA = fminf(mnA,ya);
      sB += yb; qB = fmaf(yb,yb,qB); mxB = fmaxf(mxB,yb); mnB = fminf(mnB,yb);
    }
  }

  float4* st = reinterpret_cast<float4*>(&sm->feat.stat[w][lane][0]);
  st[0] = make_float4(sA,qA,mxA,mnA);
  st[1] = make_float4(sB,qB,mxB,mnB);
  __syncthreads();
  if (w == 0) {
    float4 aA = *reinterpret_cast<float4*>(&sm->feat.stat[0][lane][0]);
    float4 aB = *reinterpret_cast<float4*>(&sm->feat.stat[0][lane][4]);
#pragma unroll
    for (int q = 1; q < 4; q++) {
      const float4 cA = *reinterpret_cast<float4*>(&sm->feat.stat[q][lane][0]);
      const float4 cB = *reinterpret_cast<float4*>(&sm->feat.stat[q][lane][4]);
      aA.x += cA.x; aA.y += cA.y; aA.z = fmaxf(aA.z,cA.z); aA.w = fminf(aA.w,cA.w);
      aB.x += cB.x; aB.y += cB.y; aB.z = fmaxf(aB.z,cB.z); aB.w = fminf(aB.w,cB.w);
    }
    float* pb = partialsB + (size_t)fbid * 512;
    pb[0*128 +      lane] = aA.x; pb[1*128 +      lane] = aA.y;
    pb[2*128 +      lane] = aA.z; pb[3*128 +      lane] = aA.w;
    pb[0*128 + 64 + lane] = aB.x; pb[1*128 + 64 + lane] = aB.y;
    pb[2*128 + 64 + lane] = aB.z; pb[3*128 + 64 + lane] = aB.w;
  }
}

// ---------------- fused level kernel: blocks 0..63 = FPS, rest = feature pass ----------------
template<int NPTS, bool HASFPS>
__global__ __launch_bounds__(256, 2) void level_main(const float* __restrict__ pts,
    const float* __restrict__ W1f, const float* __restrict__ w2,
    float* __restrict__ partialsB, float* __restrict__ ptsNext, float* __restrict__ momNext) {
  __shared__ SMem sm;
  if (HASFPS && blockIdx.x < 64) { fps_body<NPTS>(pts, ptsNext, momNext, &sm); return; }
  const int fbid = HASFPS ? (int)blockIdx.x - 64 : (int)blockIdx.x;
  featB_body<NPTS>(pts, W1f, w2, partialsB, fbid, &sm);
}

// ---------------- level-0 moment reduction (9 moments of xyz) ----------------
__global__ __launch_bounds__(256) void mom0_kernel(const float* __restrict__ pts,
                                                   float* __restrict__ mp) {
  __shared__ float red[256];
  const int tid = threadIdx.x;
  float acc[9] = {0,0,0,0,0,0,0,0,0};
#pragma unroll
  for (int i = 0; i < 4; i++) {
    const size_t j = (size_t)blockIdx.x * 1024 + (size_t)i * 256 + tid;
    const float x = pts[3*j], y = pts[3*j+1], z = pts[3*j+2];
    acc[0]+=x; acc[1]+=y; acc[2]+=z;
    acc[3]=fmaf(x,x,acc[3]); acc[4]=fmaf(y,y,acc[4]); acc[5]=fmaf(z,z,acc[5]);
    acc[6]=fmaf(x,y,acc[6]); acc[7]=fmaf(x,z,acc[7]); acc[8]=fmaf(y,z,acc[8]);
  }
  for (int k = 0; k < 9; k++) {
    red[tid] = acc[k]; __syncthreads();
    for (int s = 128; s > 0; s >>= 1) { if (tid < s) red[tid] += red[tid+s]; __syncthreads(); }
    if (tid == 0) mp[blockIdx.x*9 + k] = red[0];
    __syncthreads();
  }
}

// ---------------- fold layer-1 BN into weights via moments ----------------
__global__ __launch_bounds__(64) void fin1_kernel(const float* __restrict__ mom, int npart,
    float Pinv, const float* __restrict__ w1, const float* __restrict__ g1,
    const float* __restrict__ be1, float* __restrict__ W1f) {
  __shared__ float M[9];
  const int t = threadIdx.x;
  if (t < 9) { float s = 0.f; for (int i = 0; i < npart; i++) s += mom[i*9 + t]; M[t] = s; }
  __syncthreads();
  const float w0 = w1[0*64 + t], w1_ = w1[1*64 + t], w2_ = w1[2*64 + t];
  const float mean = (w0*M[0] + w1_*M[1] + w2_*M[2]) * Pinv;
  const float ey2  = (w0*w0*M[3] + w1_*w1_*M[4] + w2_*w2_*M[5]
                    + 2.f*(w0*w1_*M[6] + w0*w2_*M[7] + w1_*w2_*M[8])) * Pinv;
  const float var  = fmaxf(ey2 - mean*mean, 0.f);
  const float a    = g1[t] * rsqrtf(var + BN_EPS);
  float4 r; r.x = a*w0; r.y = a*w1_; r.z = a*w2_; r.w = fmaf(-a, mean, be1[t]);
  *reinterpret_cast<float4*>(&W1f[t*4]) = r;
}

// ---------------- layer-2 BN coefficients from per-block partial sums ----------------
__global__ __launch_bounds__(128) void f2a_kernel(const float* __restrict__ partialsB, int nb,
    float Pinv, const float* __restrict__ g2, const float* __restrict__ be2,
    float* __restrict__ a2c2) {
  const int ch = threadIdx.x;
  float s = 0.f, q = 0.f;
  for (int i = 0; i < nb; i++) {
    s += partialsB[(size_t)i*512 + ch];
    q += partialsB[(size_t)i*512 + 128 + ch];
  }
  const float mean = s * Pinv;
  const float var  = fmaxf(q * Pinv - mean*mean, 0.f);
  const float a    = g2[ch] * rsqrtf(var + BN_EPS);
  a2c2[ch] = a; a2c2[128 + ch] = fmaf(-a, mean, be2[ch]);
}

// ---------------- final: maxpool(relu(BN2(y2))) via extremes ----------------
__global__ __launch_bounds__(128) void f2b_kernel(const float* __restrict__ partialsB, int bpb,
    const float* __restrict__ a2c2, float* __restrict__ out, int lv) {
  const int b = blockIdx.x, ch = threadIdx.x;
  const float* pb = partialsB + (size_t)b * bpb * 512;
  const float a = a2c2[ch], c = a2c2[128 + ch];
  float mx = -1e30f, mn = 1e30f;
  for (int i = 0; i < bpb; i++) {
    mx = fmaxf(mx, pb[(size_t)i*512 + 256 + ch]);
    mn = fminf(mn, pb[(size_t)i*512 + 384 + ch]);
  }
  const float v = (a >= 0.f) ? mx : mn;
  out[b*384 + lv*128 + ch] = fmaxf(0.f, fmaf(a, v, c));
}

// ---------------- host launch ----------------
extern "C" void kernel_launch(void* const* d_in, const int* in_sizes, int n_in,
                              void* d_out, int out_size, void* d_ws, size_t ws_size,
                              hipStream_t stream) {
  const float* pts = (const float*)d_in[0];
  const float* w1  = (const float*)d_in[1];
  const float* g1  = (const float*)d_in[3];
  const float* be1 = (const float*)d_in[4];
  const float* w2  = (const float*)d_in[5];
  const float* g2  = (const float*)d_in[7];
  const float* be2 = (const float*)d_in[8];
  float* out = (float*)d_out;
  float* wsf = (float*)d_ws;

  float* pts1 = wsf;               // 64*1024*3 = 196608
  float* pts2 = pts1 + 196608;     // 64*512*3  =  98304
  float* W1f  = pts2 + 98304;      // 256
  float* a2c2 = W1f  + 256;        // 256
  float* momP = a2c2 + 256;        // 1152 (max of 128*9, 64*9)
  float* partB= momP + 1152;       // 512*512 = 262144

  // ---- level 0 (N=2048, P=131072) ----
  mom0_kernel<<<128, 256, 0, stream>>>(pts, momP);
  fin1_kernel<<<1, 64, 0, stream>>>(momP, 128, 1.f/131072.f, w1, g1, be1, W1f);
  level_main<2048, true><<<64 + 512, 256, 0, stream>>>(pts, W1f, w2, partB, pts1, momP);
  f2a_kernel<<<1, 128, 0, stream>>>(partB, 512, 1.f/131072.f, g2, be2, a2c2);
  f2b_kernel<<<64, 128, 0, stream>>>(partB, 8, a2c2, out, 0);

  // ---- level 1 (N=1024, P=65536) ----
  fin1_kernel<<<1, 64, 0, stream>>>(momP, 64, 1.f/65536.f, w1 + 192, g1 + 64, be1 + 64, W1f);
  level_main<1024, true><<<64 + 256, 256, 0, stream>>>(pts1, W1f, w2 + 8192, partB, pts2, momP);
  f2a_kernel<<<1, 128, 0, stream>>>(partB, 256, 1.f/65536.f, g2 + 128, be2 + 128, a2c2);
  f2b_kernel<<<64, 128, 0, stream>>>(partB, 4, a2c2, out, 1);

  // ---- level 2 (N=512, P=32768, no FPS) ----
  fin1_kernel<<<1, 64, 0, stream>>>(momP, 64, 1.f/32768.f, w1 + 384, g1 + 128, be1 + 128, W1f);
  level_main<512, false><<<128, 256, 0, stream>>>(pts2, W1f, w2 + 16384, partB, wsf, wsf);
  f2a_kernel<<<1, 128, 0, stream>>>(partB, 128, 1.f/32768.f, g2 + 256, be2 + 256, a2c2);
  f2b_kernel<<<64, 128, 0, stream>>>(partB, 2, a2c2, out, 2);
}

// Round 6
// 1129.591 us; speedup vs baseline: 1.2425x; 1.2425x over previous
//
#include <hip/hip_runtime.h>

#define BN_EPS 1e-5f

typedef unsigned long long u64;

// ---------------- shared-memory union ----------------
struct FpsSm {
  uint4 slotD[2][4];   // per wave: {dist_bits, ~j, x_bits, y_bits}, parity-buffered
  float slotZ[2][4];   // z
  float sel[3 * 1024]; // selected points, flushed once at end
};
struct FeatSm {
  float W1s[256];        // folded layer-1 weights: [c][4] = a*w0,a*w1,a*w2, be-a*mean
  float h1s[128][68];    // padded rows (68 floats = 272B, 16B aligned)
  float stat[4][64][8];  // per-wave partial stats
};
union __align__(16) SMem { FpsSm fps; FeatSm feat; };

// ---------------- fast wave-wide max (DPP) ----------------
#if __has_builtin(__builtin_amdgcn_update_dpp) && __has_builtin(__builtin_amdgcn_readlane)
template<int CTRL>
__device__ __forceinline__ float dppmax(float x) {
  const int t = __builtin_amdgcn_update_dpp(0, __float_as_int(x), CTRL, 0xf, 0xf, true);
  return fmaxf(x, __int_as_float(t));
}
__device__ __forceinline__ float wave_max_f32(float x) {
  x = dppmax<0x111>(x);  // row_shr:1
  x = dppmax<0x112>(x);  // row_shr:2
  x = dppmax<0x114>(x);  // row_shr:4
  x = dppmax<0x118>(x);  // row_shr:8
  x = dppmax<0x142>(x);  // row_bcast15
  x = dppmax<0x143>(x);  // row_bcast31
  return __int_as_float(__builtin_amdgcn_readlane(__float_as_int(x), 63));
}
#else
__device__ __forceinline__ float wave_max_f32(float x) {
  for (int off = 32; off; off >>= 1) x = fmaxf(x, __shfl_xor(x, off));
  return x;
}
#endif

// ---------------- FPS: 4 waves, barrier exchange, winner-lane direct publish ----------------
template<int NPTS>
__device__ void fps_body(const float* __restrict__ pts, float* __restrict__ ptsNext,
                         float* __restrict__ momNext, SMem* sm) {
  constexpr int R = NPTS / 256;
  constexpr int M = NPTS / 2;
  const int b    = blockIdx.x;
  const int tid  = threadIdx.x;
  const int lane = tid & 63;
  const int w    = tid >> 6;
  const float* p0 = pts + (size_t)b * NPTS * 3;
  float* sel = sm->fps.sel;

  float px[R], py[R], pz[R], mind[R];
#pragma unroll
  for (int i = 0; i < R; i++) {
    const int j = tid + 256 * i;
    px[i] = p0[3*j]; py[i] = p0[3*j+1]; pz[i] = p0[3*j+2];
  }

  float sx = p0[0], sy = p0[1], sz = p0[2];
  if (tid == 0) { sel[0] = sx; sel[1] = sy; sel[2] = sz; }

  // per-lane best: value, global index, coords (carried via cndmask)
  float bv = -1.0f, bx = 0.f, by = 0.f, bz = 0.f; int bj = 0;
#pragma unroll
  for (int i = 0; i < R; i++) {
    const float dx = px[i]-sx, dy = py[i]-sy, dz = pz[i]-sz;
    const float d = __fadd_rn(__fadd_rn(__fmul_rn(dx,dx), __fmul_rn(dy,dy)), __fmul_rn(dz,dz));
    mind[i] = d;
    if (d > bv) { bv = d; bj = tid + 256*i; bx = px[i]; by = py[i]; bz = pz[i]; }
  }

  for (int it = 1; it < M; ++it) {
    // --- wave-level: value max via DPP; winner lane self-identifies ---
    const float smax = wave_max_f32(bv);
    bool win = (bv == smax);
    if (__popcll(__ballot(win)) > 1) {   // exact ties (rare): first (lowest) index wins
      int jj = win ? bj : 0x7fffffff;
#pragma unroll
      for (int off = 32; off; off >>= 1) jj = min(jj, __shfl_xor(jj, off));
      win = win && (bj == jj);
    }

    // --- publish: the single winning lane writes its own registers (no readlanes) ---
    const int par = it & 1;
    if (win) {
      sm->fps.slotD[par][w] = make_uint4(__float_as_uint(bv), ~(unsigned)bj,
                                         __float_as_uint(bx), __float_as_uint(by));
      sm->fps.slotZ[par][w] = bz;
    }
    __syncthreads();

    // --- combine 4 candidates (64-bit key = dist_bits:~j; max = farthest, ties->lowest j) ---
    const uint4 k0 = sm->fps.slotD[par][0], k1 = sm->fps.slotD[par][1];
    const uint4 k2 = sm->fps.slotD[par][2], k3 = sm->fps.slotD[par][3];
    const float z0 = sm->fps.slotZ[par][0], z1 = sm->fps.slotZ[par][1];
    const float z2 = sm->fps.slotZ[par][2], z3 = sm->fps.slotZ[par][3];
    const u64 K0 = ((u64)k0.x << 32) | k0.y;
    const u64 K1 = ((u64)k1.x << 32) | k1.y;
    const u64 K2 = ((u64)k2.x << 32) | k2.y;
    const u64 K3 = ((u64)k3.x << 32) | k3.y;
    const bool a01 = K1 > K0, a23 = K3 > K2;
    const u64 Ka = a01 ? K1 : K0, Kb = a23 ? K3 : K2;
    const uint4 kA = a01 ? k1 : k0, kB = a23 ? k3 : k2;
    const float zA = a01 ? z1 : z0, zB = a23 ? z3 : z2;
    const bool ab = Kb > Ka;
    const uint4 kW = ab ? kB : kA;
    sx = __uint_as_float(kW.z); sy = __uint_as_float(kW.w); sz = ab ? zB : zA;

    if (tid == 0) { sel[3*it] = sx; sel[3*it+1] = sy; sel[3*it+2] = sz; }

    // --- distance update + per-lane argmax scan ---
    bv = -1.0f; bj = 0;
#pragma unroll
    for (int i = 0; i < R; i++) {
      const float dx = px[i]-sx, dy = py[i]-sy, dz = pz[i]-sz;
      const float d = __fadd_rn(__fadd_rn(__fmul_rn(dx,dx), __fmul_rn(dy,dy)), __fmul_rn(dz,dz));
      const float mv = fminf(mind[i], d);
      mind[i] = mv;
      if (mv > bv) { bv = mv; bj = tid + 256*i; bx = px[i]; by = py[i]; bz = pz[i]; }
    }
  }

  __syncthreads();   // sel[] complete
  // bulk coalesced flush of selected points (LDS -> global), once
  float* o = ptsNext + (size_t)b * M * 3;
#pragma unroll 4
  for (int e = tid; e < 3 * M; e += 256) o[e] = sel[e];

  // moments of the selected set (for next level's layer-1 BN), computed once by wave 0
  if (w == 0) {
    float m0=0.f,m1=0.f,m2=0.f,m3=0.f,m4=0.f,m5=0.f,m6=0.f,m7=0.f,m8=0.f;
    for (int k = lane; k < M; k += 64) {
      const float x = sel[3*k], y = sel[3*k+1], z = sel[3*k+2];
      m0 += x; m1 += y; m2 += z;
      m3 = fmaf(x,x,m3); m4 = fmaf(y,y,m4); m5 = fmaf(z,z,m5);
      m6 = fmaf(x,y,m6); m7 = fmaf(x,z,m7); m8 = fmaf(y,z,m8);
    }
#pragma unroll
    for (int off = 32; off; off >>= 1) {
      m0 += __shfl_xor(m0, off); m1 += __shfl_xor(m1, off); m2 += __shfl_xor(m2, off);
      m3 += __shfl_xor(m3, off); m4 += __shfl_xor(m4, off); m5 += __shfl_xor(m5, off);
      m6 += __shfl_xor(m6, off); m7 += __shfl_xor(m7, off); m8 += __shfl_xor(m8, off);
    }
    if (lane == 0) {
      float* mo = momNext + b * 9;
      mo[0]=m0; mo[1]=m1; mo[2]=m2; mo[3]=m3; mo[4]=m4; mo[5]=m5; mo[6]=m6; mo[7]=m7; mo[8]=m8;
    }
  }
}

// ---------------- feature pass: h1=relu(BN1(x@w1)), y2=h1@w2; stats+extremes ----------------
template<int NPTS>
__device__ void featB_body(const float* __restrict__ pts, const float* __restrict__ W1f,
                           const float* __restrict__ w2, float* __restrict__ partialsB,
                           int fbid, SMem* sm) {
  const int tid  = threadIdx.x;
  const int lane = tid & 63;
  const int w    = tid >> 6;
  constexpr int BPB = NPTS / 256;       // blocks per batch
  const int b = fbid / BPB;
  const size_t pbase = (size_t)b * NPTS + (size_t)(fbid % BPB) * 256;

  float* W1s = sm->feat.W1s;
  W1s[tid < 256 ? tid : 0] = W1f[tid < 256 ? tid : 0];
  __syncthreads();

  // per-lane layer-2 weight columns: channel `lane` and `lane+64`
  float wA[64], wB[64];
#pragma unroll
  for (int k = 0; k < 64; k++) { wA[k] = w2[k*128 + lane]; wB[k] = w2[k*128 + 64 + lane]; }

  float sA=0.f, qA=0.f, sB=0.f, qB=0.f;
  float mxA=-1e30f, mnA=1e30f, mxB=-1e30f, mnB=1e30f;

  for (int r = 0; r < 2; r++) {
    __syncthreads();                     // protect h1s overwrite vs previous round's reads
    if (tid < 128) {                     // phase A: compute h1 for 128 points
      const float* pp = pts + (pbase + (size_t)r*128 + tid) * 3;
      const float x = pp[0], y = pp[1], z = pp[2];
#pragma unroll
      for (int k = 0; k < 64; k += 4) {
        float4 hv;
        { const float4 wf = *reinterpret_cast<const float4*>(&W1s[4*(k  )]);
          hv.x = fmaxf(0.f, fmaf(x,wf.x, fmaf(y,wf.y, fmaf(z,wf.z, wf.w)))); }
        { const float4 wf = *reinterpret_cast<const float4*>(&W1s[4*(k+1)]);
          hv.y = fmaxf(0.f, fmaf(x,wf.x, fmaf(y,wf.y, fmaf(z,wf.z, wf.w)))); }
        { const float4 wf = *reinterpret_cast<const float4*>(&W1s[4*(k+2)]);
          hv.z = fmaxf(0.f, fmaf(x,wf.x, fmaf(y,wf.y, fmaf(z,wf.z, wf.w)))); }
        { const float4 wf = *reinterpret_cast<const float4*>(&W1s[4*(k+3)]);
          hv.w = fmaxf(0.f, fmaf(x,wf.x, fmaf(y,wf.y, fmaf(z,wf.z, wf.w)))); }
        *reinterpret_cast<float4*>(&sm->feat.h1s[tid][k]) = hv;
      }
    }
    __syncthreads();
    // phase B: wave w consumes rows [w*32, w*32+32)
    const int row0 = w * 32;
    for (int p = row0; p < row0 + 32; ++p) {
      float ya = 0.f, yb = 0.f;
#pragma unroll
      for (int k = 0; k < 64; k += 4) {
        const float4 hv = *reinterpret_cast<const float4*>(&sm->feat.h1s[p][k]);
        ya = fmaf(hv.x, wA[k  ], ya);  yb = fmaf(hv.x, wB[k  ], yb);
        ya = fmaf(hv.y, wA[k+1], ya);  yb = fmaf(hv.y, wB[k+1], yb);
        ya = fmaf(hv.z, wA[k+2], ya);  yb = fmaf(hv.z, wB[k+2], yb);
        ya = fmaf(hv.w, wA[k+3], ya);  yb = fmaf(hv.w, wB[k+3], yb);
      }
      sA += ya; qA = fmaf(ya,ya,qA); mxA = fmaxf(mxA,ya); mnA = fminf(mnA,ya);
      sB += yb; qB = fmaf(yb,yb,qB); mxB = fmaxf(mxB,yb); mnB = fminf(mnB,yb);
    }
  }

  float4* st = reinterpret_cast<float4*>(&sm->feat.stat[w][lane][0]);
  st[0] = make_float4(sA,qA,mxA,mnA);
  st[1] = make_float4(sB,qB,mxB,mnB);
  __syncthreads();
  if (w == 0) {
    float4 aA = *reinterpret_cast<float4*>(&sm->feat.stat[0][lane][0]);
    float4 aB = *reinterpret_cast<float4*>(&sm->feat.stat[0][lane][4]);
#pragma unroll
    for (int q = 1; q < 4; q++) {
      const float4 cA = *reinterpret_cast<float4*>(&sm->feat.stat[q][lane][0]);
      const float4 cB = *reinterpret_cast<float4*>(&sm->feat.stat[q][lane][4]);
      aA.x += cA.x; aA.y += cA.y; aA.z = fmaxf(aA.z,cA.z); aA.w = fminf(aA.w,cA.w);
      aB.x += cB.x; aB.y += cB.y; aB.z = fmaxf(aB.z,cB.z); aB.w = fminf(aB.w,cB.w);
    }
    float* pb = partialsB + (size_t)fbid * 512;
    pb[0*128 +      lane] = aA.x; pb[1*128 +      lane] = aA.y;
    pb[2*128 +      lane] = aA.z; pb[3*128 +      lane] = aA.w;
    pb[0*128 + 64 + lane] = aB.x; pb[1*128 + 64 + lane] = aB.y;
    pb[2*128 + 64 + lane] = aB.z; pb[3*128 + 64 + lane] = aB.w;
  }
}

// ---------------- fused level kernel: blocks 0..63 = FPS, rest = feature pass ----------------
template<int NPTS, bool HASFPS>
__global__ __launch_bounds__(256, 2) void level_main(const float* __restrict__ pts,
    const float* __restrict__ W1f, const float* __restrict__ w2,
    float* __restrict__ partialsB, float* __restrict__ ptsNext, float* __restrict__ momNext) {
  __shared__ SMem sm;
  if (HASFPS && blockIdx.x < 64) { fps_body<NPTS>(pts, ptsNext, momNext, &sm); return; }
  const int fbid = HASFPS ? (int)blockIdx.x - 64 : (int)blockIdx.x;
  featB_body<NPTS>(pts, W1f, w2, partialsB, fbid, &sm);
}

// ---------------- level-0 moment reduction (9 moments of xyz) ----------------
__global__ __launch_bounds__(256) void mom0_kernel(const float* __restrict__ pts,
                                                   float* __restrict__ mp) {
  __shared__ float red[256];
  const int tid = threadIdx.x;
  float acc[9] = {0,0,0,0,0,0,0,0,0};
#pragma unroll
  for (int i = 0; i < 4; i++) {
    const size_t j = (size_t)blockIdx.x * 1024 + (size_t)i * 256 + tid;
    const float x = pts[3*j], y = pts[3*j+1], z = pts[3*j+2];
    acc[0]+=x; acc[1]+=y; acc[2]+=z;
    acc[3]=fmaf(x,x,acc[3]); acc[4]=fmaf(y,y,acc[4]); acc[5]=fmaf(z,z,acc[5]);
    acc[6]=fmaf(x,y,acc[6]); acc[7]=fmaf(x,z,acc[7]); acc[8]=fmaf(y,z,acc[8]);
  }
  for (int k = 0; k < 9; k++) {
    red[tid] = acc[k]; __syncthreads();
    for (int s = 128; s > 0; s >>= 1) { if (tid < s) red[tid] += red[tid+s]; __syncthreads(); }
    if (tid == 0) mp[blockIdx.x*9 + k] = red[0];
    __syncthreads();
  }
}

// ---------------- fold layer-1 BN into weights via moments ----------------
__global__ __launch_bounds__(64) void fin1_kernel(const float* __restrict__ mom, int npart,
    float Pinv, const float* __restrict__ w1, const float* __restrict__ g1,
    const float* __restrict__ be1, float* __restrict__ W1f) {
  __shared__ float M[9];
  const int t = threadIdx.x;
  if (t < 9) { float s = 0.f; for (int i = 0; i < npart; i++) s += mom[i*9 + t]; M[t] = s; }
  __syncthreads();
  const float w0 = w1[0*64 + t], w1_ = w1[1*64 + t], w2_ = w1[2*64 + t];
  const float mean = (w0*M[0] + w1_*M[1] + w2_*M[2]) * Pinv;
  const float ey2  = (w0*w0*M[3] + w1_*w1_*M[4] + w2_*w2_*M[5]
                    + 2.f*(w0*w1_*M[6] + w0*w2_*M[7] + w1_*w2_*M[8])) * Pinv;
  const float var  = fmaxf(ey2 - mean*mean, 0.f);
  const float a    = g1[t] * rsqrtf(var + BN_EPS);
  float4 r; r.x = a*w0; r.y = a*w1_; r.z = a*w2_; r.w = fmaf(-a, mean, be1[t]);
  *reinterpret_cast<float4*>(&W1f[t*4]) = r;
}

// ---------------- layer-2 BN coefficients from per-block partial sums ----------------
__global__ __launch_bounds__(128) void f2a_kernel(const float* __restrict__ partialsB, int nb,
    float Pinv, const float* __restrict__ g2, const float* __restrict__ be2,
    float* __restrict__ a2c2) {
  const int ch = threadIdx.x;
  float s = 0.f, q = 0.f;
  for (int i = 0; i < nb; i++) {
    s += partialsB[(size_t)i*512 + ch];
    q += partialsB[(size_t)i*512 + 128 + ch];
  }
  const float mean = s * Pinv;
  const float var  = fmaxf(q * Pinv - mean*mean, 0.f);
  const float a    = g2[ch] * rsqrtf(var + BN_EPS);
  a2c2[ch] = a; a2c2[128 + ch] = fmaf(-a, mean, be2[ch]);
}

// ---------------- final: maxpool(relu(BN2(y2))) via extremes ----------------
__global__ __launch_bounds__(128) void f2b_kernel(const float* __restrict__ partialsB, int bpb,
    const float* __restrict__ a2c2, float* __restrict__ out, int lv) {
  const int b = blockIdx.x, ch = threadIdx.x;
  const float* pb = partialsB + (size_t)b * bpb * 512;
  const float a = a2c2[ch], c = a2c2[128 + ch];
  float mx = -1e30f, mn = 1e30f;
  for (int i = 0; i < bpb; i++) {
    mx = fmaxf(mx, pb[(size_t)i*512 + 256 + ch]);
    mn = fminf(mn, pb[(size_t)i*512 + 384 + ch]);
  }
  const float v = (a >= 0.f) ? mx : mn;
  out[b*384 + lv*128 + ch] = fmaxf(0.f, fmaf(a, v, c));
}

// ---------------- host launch ----------------
extern "C" void kernel_launch(void* const* d_in, const int* in_sizes, int n_in,
                              void* d_out, int out_size, void* d_ws, size_t ws_size,
                              hipStream_t stream) {
  const float* pts = (const float*)d_in[0];
  const float* w1  = (const float*)d_in[1];
  const float* g1  = (const float*)d_in[3];
  const float* be1 = (const float*)d_in[4];
  const float* w2  = (const float*)d_in[5];
  const float* g2  = (const float*)d_in[7];
  const float* be2 = (const float*)d_in[8];
  float* out = (float*)d_out;
  float* wsf = (float*)d_ws;

  float* pts1 = wsf;               // 64*1024*3 = 196608
  float* pts2 = pts1 + 196608;     // 64*512*3  =  98304
  float* W1f  = pts2 + 98304;      // 256
  float* a2c2 = W1f  + 256;        // 256
  float* momP = a2c2 + 256;        // 1152 (max of 128*9, 64*9)
  float* partB= momP + 1152;       // 512*512 = 262144

  // ---- level 0 (N=2048, P=131072) ----
  mom0_kernel<<<128, 256, 0, stream>>>(pts, momP);
  fin1_kernel<<<1, 64, 0, stream>>>(momP, 128, 1.f/131072.f, w1, g1, be1, W1f);
  level_main<2048, true><<<64 + 512, 256, 0, stream>>>(pts, W1f, w2, partB, pts1, momP);
  f2a_kernel<<<1, 128, 0, stream>>>(partB, 512, 1.f/131072.f, g2, be2, a2c2);
  f2b_kernel<<<64, 128, 0, stream>>>(partB, 8, a2c2, out, 0);

  // ---- level 1 (N=1024, P=65536) ----
  fin1_kernel<<<1, 64, 0, stream>>>(momP, 64, 1.f/65536.f, w1 + 192, g1 + 64, be1 + 64, W1f);
  level_main<1024, true><<<64 + 256, 256, 0, stream>>>(pts1, W1f, w2 + 8192, partB, pts2, momP);
  f2a_kernel<<<1, 128, 0, stream>>>(partB, 256, 1.f/65536.f, g2 + 128, be2 + 128, a2c2);
  f2b_kernel<<<64, 128, 0, stream>>>(partB, 4, a2c2, out, 1);

  // ---- level 2 (N=512, P=32768, no FPS) ----
  fin1_kernel<<<1, 64, 0, stream>>>(momP, 64, 1.f/32768.f, w1 + 384, g1 + 128, be1 + 128, W1f);
  level_main<512, false><<<128, 256, 0, stream>>>(pts2, W1f, w2 + 16384, partB, wsf, wsf);
  f2a_kernel<<<1, 128, 0, stream>>>(partB, 128, 1.f/32768.f, g2 + 256, be2 + 256, a2c2);
  f2b_kernel<<<64, 128, 0, stream>>>(partB, 2, a2c2, out, 2);
}

// Round 7
// 941.152 us; speedup vs baseline: 1.4913x; 1.2002x over previous
//
#include <hip/hip_runtime.h>

#define BN_EPS 1e-5f

typedef unsigned long long u64;

// ---------------- shared-memory union ----------------
struct FpsSm {
  uint4 slotD[2][4];   // per wave: {dist_bits, ~j, x_bits, y_bits}, parity-buffered
  float slotZ[2][4];   // z
  float sel1[3 * 1024];
  float sel2[3 * 512];
};
struct FeatSm {
  float W1s[256];        // folded layer-1 weights: [c][4] = a*w0,a*w1,a*w2, be-a*mean
  float h1s[128][68];    // padded rows (68 floats = 272B, 16B aligned)
  float stat[4][64][8];  // per-wave partial stats
};
union __align__(16) SMem { FpsSm fps; FeatSm feat; };

// ---------------- fast wave-wide max (DPP) ----------------
#if __has_builtin(__builtin_amdgcn_update_dpp) && __has_builtin(__builtin_amdgcn_readlane)
template<int CTRL>
__device__ __forceinline__ float dppmax(float x) {
  const int t = __builtin_amdgcn_update_dpp(0, __float_as_int(x), CTRL, 0xf, 0xf, true);
  return fmaxf(x, __int_as_float(t));
}
__device__ __forceinline__ float wave_max_f32(float x) {
  x = dppmax<0x111>(x);  // row_shr:1
  x = dppmax<0x112>(x);  // row_shr:2
  x = dppmax<0x114>(x);  // row_shr:4
  x = dppmax<0x118>(x);  // row_shr:8
  x = dppmax<0x142>(x);  // row_bcast15
  x = dppmax<0x143>(x);  // row_bcast31
  return __int_as_float(__builtin_amdgcn_readlane(__float_as_int(x), 63));
}
#else
__device__ __forceinline__ float wave_max_f32(float x) {
  for (int off = 32; off; off >>= 1) x = fmaxf(x, __shfl_xor(x, off));
  return x;
}
#endif

// ---------------- one FPS phase: 4 waves, barrier exchange, winner-direct publish ----------------
// src: interleaved xyz (global or LDS generic pointer). selOut: LDS, 3*M floats.
template<int NPTS>
__device__ void fps_phase(const float* __restrict__ src, float* __restrict__ selOut, FpsSm* sm) {
  constexpr int R = NPTS / 256;
  constexpr int M = NPTS / 2;
  const int tid  = threadIdx.x;
  const int lane = tid & 63;
  const int w    = tid >> 6;

  float px[R], py[R], pz[R], mind[R];
#pragma unroll
  for (int i = 0; i < R; i++) {
    const int j = tid + 256 * i;
    px[i] = src[3*j]; py[i] = src[3*j+1]; pz[i] = src[3*j+2];
  }

  float sx = src[0], sy = src[1], sz = src[2];
  if (tid == 0) { selOut[0] = sx; selOut[1] = sy; selOut[2] = sz; }

  float bv = -1.0f, bx = 0.f, by = 0.f, bz = 0.f; int bj = 0;
#pragma unroll
  for (int i = 0; i < R; i++) {
    const float dx = px[i]-sx, dy = py[i]-sy, dz = pz[i]-sz;
    const float d = __fadd_rn(__fadd_rn(__fmul_rn(dx,dx), __fmul_rn(dy,dy)), __fmul_rn(dz,dz));
    mind[i] = d;
    if (d > bv) { bv = d; bj = tid + 256*i; bx = px[i]; by = py[i]; bz = pz[i]; }
  }

  for (int it = 1; it < M; ++it) {
    // wave-level: value max via DPP; winner lane self-identifies
    const float smax = wave_max_f32(bv);
    bool win = (bv == smax);
    if (__popcll(__ballot(win)) > 1) {   // exact ties (rare): first (lowest) index wins
      int jj = win ? bj : 0x7fffffff;
#pragma unroll
      for (int off = 32; off; off >>= 1) jj = min(jj, __shfl_xor(jj, off));
      win = win && (bj == jj);
    }

    // publish: the single winning lane writes its own registers (no readlanes)
    const int par = it & 1;
    if (win) {
      sm->slotD[par][w] = make_uint4(__float_as_uint(bv), ~(unsigned)bj,
                                     __float_as_uint(bx), __float_as_uint(by));
      sm->slotZ[par][w] = bz;
    }
    __syncthreads();

    // combine 4 candidates (64-bit key = dist_bits:~j; max = farthest, ties->lowest j)
    const uint4 k0 = sm->slotD[par][0], k1 = sm->slotD[par][1];
    const uint4 k2 = sm->slotD[par][2], k3 = sm->slotD[par][3];
    const float z0 = sm->slotZ[par][0], z1 = sm->slotZ[par][1];
    const float z2 = sm->slotZ[par][2], z3 = sm->slotZ[par][3];
    const u64 K0 = ((u64)k0.x << 32) | k0.y;
    const u64 K1 = ((u64)k1.x << 32) | k1.y;
    const u64 K2 = ((u64)k2.x << 32) | k2.y;
    const u64 K3 = ((u64)k3.x << 32) | k3.y;
    const bool a01 = K1 > K0, a23 = K3 > K2;
    const u64 Ka = a01 ? K1 : K0, Kb = a23 ? K3 : K2;
    const uint4 kA = a01 ? k1 : k0, kB = a23 ? k3 : k2;
    const float zA = a01 ? z1 : z0, zB = a23 ? z3 : z2;
    const bool ab = Kb > Ka;
    const uint4 kW = ab ? kB : kA;
    sx = __uint_as_float(kW.z); sy = __uint_as_float(kW.w); sz = ab ? zB : zA;

    if (tid == 0) { selOut[3*it] = sx; selOut[3*it+1] = sy; selOut[3*it+2] = sz; }

    // distance update + per-lane argmax scan
    bv = -1.0f; bj = 0;
#pragma unroll
    for (int i = 0; i < R; i++) {
      const float dx = px[i]-sx, dy = py[i]-sy, dz = pz[i]-sz;
      const float d = __fadd_rn(__fadd_rn(__fmul_rn(dx,dx), __fmul_rn(dy,dy)), __fmul_rn(dz,dz));
      const float mv = fminf(mind[i], d);
      mind[i] = mv;
      if (mv > bv) { bv = mv; bj = tid + 256*i; bx = px[i]; by = py[i]; bz = pz[i]; }
    }
  }
}

// moments of a selected set in LDS (wave 0 only), matching prior numerics
__device__ void mom_from_sel(const float* __restrict__ sel, int M, float* __restrict__ mo, int lane) {
  float m0=0.f,m1=0.f,m2=0.f,m3=0.f,m4=0.f,m5=0.f,m6=0.f,m7=0.f,m8=0.f;
  for (int k = lane; k < M; k += 64) {
    const float x = sel[3*k], y = sel[3*k+1], z = sel[3*k+2];
    m0 += x; m1 += y; m2 += z;
    m3 = fmaf(x,x,m3); m4 = fmaf(y,y,m4); m5 = fmaf(z,z,m5);
    m6 = fmaf(x,y,m6); m7 = fmaf(x,z,m7); m8 = fmaf(y,z,m8);
  }
#pragma unroll
  for (int off = 32; off; off >>= 1) {
    m0 += __shfl_xor(m0, off); m1 += __shfl_xor(m1, off); m2 += __shfl_xor(m2, off);
    m3 += __shfl_xor(m3, off); m4 += __shfl_xor(m4, off); m5 += __shfl_xor(m5, off);
    m6 += __shfl_xor(m6, off); m7 += __shfl_xor(m7, off); m8 += __shfl_xor(m8, off);
  }
  if (lane == 0) {
    mo[0]=m0; mo[1]=m1; mo[2]=m2; mo[3]=m3; mo[4]=m4; mo[5]=m5; mo[6]=m6; mo[7]=m7; mo[8]=m8;
  }
}

// FPS chain: level-0 FPS then level-1 FPS on the selected set (still in LDS)
__device__ void fps_chain(const float* __restrict__ pts, float* __restrict__ pts1,
                          float* __restrict__ pts2, float* __restrict__ mom1,
                          float* __restrict__ mom2, FpsSm* sm) {
  const int b = blockIdx.x, tid = threadIdx.x, lane = tid & 63, w = tid >> 6;

  fps_phase<2048>(pts + (size_t)b * 2048 * 3, sm->sel1, sm);
  __syncthreads();                       // sel1 complete
  {
    float* o = pts1 + (size_t)b * 1024 * 3;
#pragma unroll 4
    for (int e = tid; e < 3 * 1024; e += 256) o[e] = sm->sel1[e];
    if (w == 0) mom_from_sel(sm->sel1, 1024, mom1 + b * 9, lane);
  }

  fps_phase<1024>(sm->sel1, sm->sel2, sm);
  __syncthreads();                       // sel2 complete
  {
    float* o = pts2 + (size_t)b * 512 * 3;
#pragma unroll 4
    for (int e = tid; e < 3 * 512; e += 256) o[e] = sm->sel2[e];
    if (w == 0) mom_from_sel(sm->sel2, 512, mom2 + b * 9, lane);
  }
}

// ---------------- feature pass: h1=relu(BN1(x@w1)), y2=h1@w2; stats+extremes ----------------
template<int NPTS>
__device__ void featB_body(const float* __restrict__ pts, const float* __restrict__ W1f,
                           const float* __restrict__ w2, float* __restrict__ partialsB,
                           int fbid, FeatSm* sm) {
  const int tid  = threadIdx.x;
  const int lane = tid & 63;
  const int w    = tid >> 6;
  constexpr int BPB = NPTS / 256;       // blocks per batch
  const int b = fbid / BPB;
  const size_t pbase = (size_t)b * NPTS + (size_t)(fbid % BPB) * 256;

  float* W1s = sm->W1s;
  W1s[tid < 256 ? tid : 0] = W1f[tid < 256 ? tid : 0];
  __syncthreads();

  float wA[64], wB[64];
#pragma unroll
  for (int k = 0; k < 64; k++) { wA[k] = w2[k*128 + lane]; wB[k] = w2[k*128 + 64 + lane]; }

  float sA=0.f, qA=0.f, sB=0.f, qB=0.f;
  float mxA=-1e30f, mnA=1e30f, mxB=-1e30f, mnB=1e30f;

  for (int r = 0; r < 2; r++) {
    __syncthreads();
    if (tid < 128) {
      const float* pp = pts + (pbase + (size_t)r*128 + tid) * 3;
      const float x = pp[0], y = pp[1], z = pp[2];
#pragma unroll
      for (int k = 0; k < 64; k += 4) {
        float4 hv;
        { const float4 wf = *reinterpret_cast<const float4*>(&W1s[4*(k  )]);
          hv.x = fmaxf(0.f, fmaf(x,wf.x, fmaf(y,wf.y, fmaf(z,wf.z, wf.w)))); }
        { const float4 wf = *reinterpret_cast<const float4*>(&W1s[4*(k+1)]);
          hv.y = fmaxf(0.f, fmaf(x,wf.x, fmaf(y,wf.y, fmaf(z,wf.z, wf.w)))); }
        { const float4 wf = *reinterpret_cast<const float4*>(&W1s[4*(k+2)]);
          hv.z = fmaxf(0.f, fmaf(x,wf.x, fmaf(y,wf.y, fmaf(z,wf.z, wf.w)))); }
        { const float4 wf = *reinterpret_cast<const float4*>(&W1s[4*(k+3)]);
          hv.w = fmaxf(0.f, fmaf(x,wf.x, fmaf(y,wf.y, fmaf(z,wf.z, wf.w)))); }
        *reinterpret_cast<float4*>(&sm->h1s[tid][k]) = hv;
      }
    }
    __syncthreads();
    const int row0 = w * 32;
    for (int p = row0; p < row0 + 32; ++p) {
      float ya = 0.f, yb = 0.f;
#pragma unroll
      for (int k = 0; k < 64; k += 4) {
        const float4 hv = *reinterpret_cast<const float4*>(&sm->h1s[p][k]);
        ya = fmaf(hv.x, wA[k  ], ya);  yb = fmaf(hv.x, wB[k  ], yb);
        ya = fmaf(hv.y, wA[k+1], ya);  yb = fmaf(hv.y, wB[k+1], yb);
        ya = fmaf(hv.z, wA[k+2], ya);  yb = fmaf(hv.z, wB[k+2], yb);
        ya = fmaf(hv.w, wA[k+3], ya);  yb = fmaf(hv.w, wB[k+3], yb);
      }
      sA += ya; qA = fmaf(ya,ya,qA); mxA = fmaxf(mxA,ya); mnA = fminf(mnA,ya);
      sB += yb; qB = fmaf(yb,yb,qB); mxB = fmaxf(mxB,yb); mnB = fminf(mnB,yb);
    }
  }

  float4* st = reinterpret_cast<float4*>(&sm->stat[w][lane][0]);
  st[0] = make_float4(sA,qA,mxA,mnA);
  st[1] = make_float4(sB,qB,mxB,mnB);
  __syncthreads();
  if (w == 0) {
    float4 aA = *reinterpret_cast<float4*>(&sm->stat[0][lane][0]);
    float4 aB = *reinterpret_cast<float4*>(&sm->stat[0][lane][4]);
#pragma unroll
    for (int q = 1; q < 4; q++) {
      const float4 cA = *reinterpret_cast<float4*>(&sm->stat[q][lane][0]);
      const float4 cB = *reinterpret_cast<float4*>(&sm->stat[q][lane][4]);
      aA.x += cA.x; aA.y += cA.y; aA.z = fmaxf(aA.z,cA.z); aA.w = fminf(aA.w,cA.w);
      aB.x += cB.x; aB.y += cB.y; aB.z = fmaxf(aB.z,cB.z); aB.w = fminf(aB.w,cB.w);
    }
    float* pb = partialsB + (size_t)fbid * 512;
    pb[0*128 +      lane] = aA.x; pb[1*128 +      lane] = aA.y;
    pb[2*128 +      lane] = aA.z; pb[3*128 +      lane] = aA.w;
    pb[0*128 + 64 + lane] = aB.x; pb[1*128 + 64 + lane] = aB.y;
    pb[2*128 + 64 + lane] = aB.z; pb[3*128 + 64 + lane] = aB.w;
  }
}

// ---------------- K_A: blocks 0..63 = fused FPS0+FPS1, rest = feat level-0 ----------------
__global__ __launch_bounds__(256, 2) void kA_kernel(const float* __restrict__ pts,
    const float* __restrict__ W1f0, const float* __restrict__ w2, float* __restrict__ partB0,
    float* __restrict__ pts1, float* __restrict__ pts2,
    float* __restrict__ mom1, float* __restrict__ mom2) {
  __shared__ SMem sm;
  if (blockIdx.x < 64) { fps_chain(pts, pts1, pts2, mom1, mom2, &sm.fps); return; }
  featB_body<2048>(pts, W1f0, w2, partB0, (int)blockIdx.x - 64, &sm.feat);
}

// ---------------- K_B: feat level-1 (256 blocks) + feat level-2 (128 blocks) ----------------
__global__ __launch_bounds__(256, 2) void kB_kernel(const float* __restrict__ pts1,
    const float* __restrict__ pts2, const float* __restrict__ W1f1, const float* __restrict__ W1f2,
    const float* __restrict__ w2, float* __restrict__ partB1, float* __restrict__ partB2) {
  __shared__ SMem sm;
  if (blockIdx.x < 256) featB_body<1024>(pts1, W1f1, w2 + 8192,  partB1, (int)blockIdx.x,       &sm.feat);
  else                  featB_body< 512>(pts2, W1f2, w2 + 16384, partB2, (int)blockIdx.x - 256, &sm.feat);
}

// ---------------- level-0 moment reduction (9 moments of xyz) ----------------
__global__ __launch_bounds__(256) void mom0_kernel(const float* __restrict__ pts,
                                                   float* __restrict__ mp) {
  __shared__ float red[256];
  const int tid = threadIdx.x;
  float acc[9] = {0,0,0,0,0,0,0,0,0};
#pragma unroll
  for (int i = 0; i < 4; i++) {
    const size_t j = (size_t)blockIdx.x * 1024 + (size_t)i * 256 + tid;
    const float x = pts[3*j], y = pts[3*j+1], z = pts[3*j+2];
    acc[0]+=x; acc[1]+=y; acc[2]+=z;
    acc[3]=fmaf(x,x,acc[3]); acc[4]=fmaf(y,y,acc[4]); acc[5]=fmaf(z,z,acc[5]);
    acc[6]=fmaf(x,y,acc[6]); acc[7]=fmaf(x,z,acc[7]); acc[8]=fmaf(y,z,acc[8]);
  }
  for (int k = 0; k < 9; k++) {
    red[tid] = acc[k]; __syncthreads();
    for (int s = 128; s > 0; s >>= 1) { if (tid < s) red[tid] += red[tid+s]; __syncthreads(); }
    if (tid == 0) mp[blockIdx.x*9 + k] = red[0];
    __syncthreads();
  }
}

// ---------------- fold layer-1 BN into weights via moments (body, 128-thread safe) ----------------
__device__ void fin1_body(const float* __restrict__ mom, int npart, float Pinv,
    const float* __restrict__ w1, const float* __restrict__ g1,
    const float* __restrict__ be1, float* __restrict__ W1f, float* M) {
  const int t = threadIdx.x;
  if (t < 9) { float s = 0.f; for (int i = 0; i < npart; i++) s += mom[i*9 + t]; M[t] = s; }
  __syncthreads();
  if (t < 64) {
    const float w0 = w1[0*64 + t], w1_ = w1[1*64 + t], w2_ = w1[2*64 + t];
    const float mean = (w0*M[0] + w1_*M[1] + w2_*M[2]) * Pinv;
    const float ey2  = (w0*w0*M[3] + w1_*w1_*M[4] + w2_*w2_*M[5]
                      + 2.f*(w0*w1_*M[6] + w0*w2_*M[7] + w1_*w2_*M[8])) * Pinv;
    const float var  = fmaxf(ey2 - mean*mean, 0.f);
    const float a    = g1[t] * rsqrtf(var + BN_EPS);
    float4 r; r.x = a*w0; r.y = a*w1_; r.z = a*w2_; r.w = fmaf(-a, mean, be1[t]);
    *reinterpret_cast<float4*>(&W1f[t*4]) = r;
  }
}

__global__ __launch_bounds__(64) void fin1_kernel(const float* __restrict__ mom, int npart,
    float Pinv, const float* __restrict__ w1, const float* __restrict__ g1,
    const float* __restrict__ be1, float* __restrict__ W1f) {
  __shared__ float M[9];
  fin1_body(mom, npart, Pinv, w1, g1, be1, W1f, M);
}

// ---------------- fused BN2-coeffs + maxpool(relu(BN2(y2))) per batch ----------------
__device__ void f2ab_body(const float* __restrict__ partB, int nb, int bpb, float Pinv,
    const float* __restrict__ g2, const float* __restrict__ be2,
    float* __restrict__ out, int lv, int b) {
  const int ch = threadIdx.x;   // 128 threads
  float s = 0.f, q = 0.f;
  for (int i = 0; i < nb; i++) {
    s += partB[(size_t)i*512 + ch];
    q += partB[(size_t)i*512 + 128 + ch];
  }
  const float mean = s * Pinv;
  const float var  = fmaxf(q * Pinv - mean*mean, 0.f);
  const float a    = g2[ch] * rsqrtf(var + BN_EPS);
  const float c    = fmaf(-a, mean, be2[ch]);
  const float* pb = partB + (size_t)b * bpb * 512;
  float mx = -1e30f, mn = 1e30f;
  for (int i = 0; i < bpb; i++) {
    mx = fmaxf(mx, pb[(size_t)i*512 + 256 + ch]);
    mn = fminf(mn, pb[(size_t)i*512 + 384 + ch]);
  }
  const float v = (a >= 0.f) ? mx : mn;
  out[b*384 + lv*128 + ch] = fmaxf(0.f, fmaf(a, v, c));
}

// post0: blocks 0-63 = f2ab level-0; block 64/65 = fin1 for levels 1/2
__global__ __launch_bounds__(128) void post0_kernel(const float* __restrict__ partB0,
    const float* __restrict__ mom1, const float* __restrict__ mom2,
    const float* __restrict__ w1, const float* __restrict__ g1, const float* __restrict__ be1,
    const float* __restrict__ g2, const float* __restrict__ be2,
    float* __restrict__ W1f1, float* __restrict__ W1f2, float* __restrict__ out) {
  __shared__ float M[9];
  if (blockIdx.x < 64)       f2ab_body(partB0, 512, 8, 1.f/131072.f, g2, be2, out, 0, (int)blockIdx.x);
  else if (blockIdx.x == 64) fin1_body(mom1, 64, 1.f/65536.f, w1 + 192, g1 + 64,  be1 + 64,  W1f1, M);
  else                       fin1_body(mom2, 64, 1.f/32768.f, w1 + 384, g1 + 128, be1 + 128, W1f2, M);
}

// postF: blocks 0-63 = f2ab level-1; blocks 64-127 = f2ab level-2
__global__ __launch_bounds__(128) void postF_kernel(const float* __restrict__ partB1,
    const float* __restrict__ partB2, const float* __restrict__ g2,
    const float* __restrict__ be2, float* __restrict__ out) {
  if (blockIdx.x < 64) f2ab_body(partB1, 256, 4, 1.f/65536.f, g2 + 128, be2 + 128, out, 1, (int)blockIdx.x);
  else                 f2ab_body(partB2, 128, 2, 1.f/32768.f, g2 + 256, be2 + 256, out, 2, (int)blockIdx.x - 64);
}

// ---------------- host launch ----------------
extern "C" void kernel_launch(void* const* d_in, const int* in_sizes, int n_in,
                              void* d_out, int out_size, void* d_ws, size_t ws_size,
                              hipStream_t stream) {
  const float* pts = (const float*)d_in[0];
  const float* w1  = (const float*)d_in[1];
  const float* g1  = (const float*)d_in[3];
  const float* be1 = (const float*)d_in[4];
  const float* w2  = (const float*)d_in[5];
  const float* g2  = (const float*)d_in[7];
  const float* be2 = (const float*)d_in[8];
  float* out = (float*)d_out;
  float* wsf = (float*)d_ws;

  float* pts1  = wsf;                 // 196608
  float* pts2  = pts1  + 196608;      //  98304
  float* W1f0  = pts2  + 98304;       //     256
  float* W1f1  = W1f0  + 256;         //     256
  float* W1f2  = W1f1  + 256;         //     256
  float* momP0 = W1f2  + 256;         //    1152 (128*9)
  float* momP1 = momP0 + 1152;        //     576 (64*9)
  float* momP2 = momP1 + 576;         //     576
  float* partB0= momP2 + 576;         //  262144 (512*512)
  float* partB1= partB0;              //  aliases partB0 (disjoint lifetime)
  float* partB2= partB0 + 131072;     //  65536

  mom0_kernel<<<128, 256, 0, stream>>>(pts, momP0);
  fin1_kernel<<<1, 64, 0, stream>>>(momP0, 128, 1.f/131072.f, w1, g1, be1, W1f0);
  kA_kernel<<<64 + 512, 256, 0, stream>>>(pts, W1f0, w2, partB0, pts1, pts2, momP1, momP2);
  post0_kernel<<<66, 128, 0, stream>>>(partB0, momP1, momP2, w1, g1, be1, g2, be2, W1f1, W1f2, out);
  kB_kernel<<<256 + 128, 256, 0, stream>>>(pts1, pts2, W1f1, W1f2, w2, partB1, partB2);
  postF_kernel<<<128, 128, 0, stream>>>(partB1, partB2, g2, be2, out);
}

// Round 8
// 694.254 us; speedup vs baseline: 2.0216x; 1.3556x over previous
//
#include <hip/hip_runtime.h>

#define BN_EPS 1e-5f

typedef unsigned long long u64;

// ---------------- shared-memory union ----------------
struct FpsSm {
  u64    slotK[2][4];    // per-wave candidate key {dist_bits,~j}, parity-buffered
  float4 P4[2048];       // packed point coords for winner gather (1 ds_read_b128)
  float  sel1[3 * 1024];
  float  sel2[3 * 512];
};
struct FeatSm {
  float W1s[256];        // folded layer-1 weights: [c][4] = a*w0,a*w1,a*w2, be-a*mean
  float h1s[128][68];    // padded rows (68 floats = 272B, 16B aligned)
  float stat[4][64][8];  // per-wave partial stats
};
union __align__(16) SMem { FpsSm fps; FeatSm feat; };

// ---------------- fast wave-wide reduce (DPP) ----------------
#if __has_builtin(__builtin_amdgcn_update_dpp) && __has_builtin(__builtin_amdgcn_readlane)
template<int CTRL>
__device__ __forceinline__ float dppmax(float x) {
  const int t = __builtin_amdgcn_update_dpp(0, __float_as_int(x), CTRL, 0xf, 0xf, true);
  return fmaxf(x, __int_as_float(t));
}
__device__ __forceinline__ float wave_max_f32(float x) {
  x = dppmax<0x111>(x); x = dppmax<0x112>(x); x = dppmax<0x114>(x);
  x = dppmax<0x118>(x); x = dppmax<0x142>(x); x = dppmax<0x143>(x);
  return __int_as_float(__builtin_amdgcn_readlane(__float_as_int(x), 63));
}
template<int CTRL>
__device__ __forceinline__ float dppsum(float x) {
  const int t = __builtin_amdgcn_update_dpp(0, __float_as_int(x), CTRL, 0xf, 0xf, true);
  return x + __int_as_float(t);
}
__device__ __forceinline__ float wave_sum_f32(float x) {
  x = dppsum<0x111>(x); x = dppsum<0x112>(x); x = dppsum<0x114>(x);
  x = dppsum<0x118>(x); x = dppsum<0x142>(x); x = dppsum<0x143>(x);
  return __int_as_float(__builtin_amdgcn_readlane(__float_as_int(x), 63));
}
#else
__device__ __forceinline__ float wave_max_f32(float x) {
  for (int off = 32; off; off >>= 1) x = fmaxf(x, __shfl_xor(x, off));
  return x;
}
__device__ __forceinline__ float wave_sum_f32(float x) {
  for (int off = 32; off; off >>= 1) x += __shfl_xor(x, off);
  return x;
}
#endif

// ---------------- one FPS phase: 4 waves, barrier exchange, key-only publish ----------------
template<int NPTS>
__device__ void fps_phase(const float* __restrict__ src, float* __restrict__ selOut, FpsSm* sm) {
  constexpr int R = NPTS / 256;
  constexpr int M = NPTS / 2;
  const int tid = threadIdx.x;
  const int w   = tid >> 6;

  float px[R], py[R], pz[R], mind[R];
#pragma unroll
  for (int i = 0; i < R; i++) {
    const int j = tid + 256 * i;
    const float x = src[3*j], y = src[3*j+1], z = src[3*j+2];
    px[i] = x; py[i] = y; pz[i] = z;
    sm->P4[j] = make_float4(x, y, z, 0.f);
  }

  float sx = src[0], sy = src[1], sz = src[2];
  if (tid == 0) { selOut[0] = sx; selOut[1] = sy; selOut[2] = sz; }

  float bv = -1.0f; int bi = 0;
#pragma unroll
  for (int i = 0; i < R; i++) {
    const float dx = px[i]-sx, dy = py[i]-sy, dz = pz[i]-sz;
    const float d = __fadd_rn(__fadd_rn(__fmul_rn(dx,dx), __fmul_rn(dy,dy)), __fmul_rn(dz,dz));
    mind[i] = d;
    if (d > bv) { bv = d; bi = i; }     // ascending i == ascending j: first max wins
  }

  for (int it = 1; it < M; ++it) {
    // wave-level: value max via DPP; winner lane self-identifies
    const float smax = wave_max_f32(bv);
    bool win = (bv == smax);
    if (__popcll(__ballot(win)) > 1) {  // exact value ties (rare): lowest global j wins
      int jj = win ? (tid + (bi << 8)) : 0x7fffffff;
#pragma unroll
      for (int off = 32; off; off >>= 1) jj = min(jj, __shfl_xor(jj, off));
      win = win && ((tid + (bi << 8)) == jj);
    }

    // publish: single u64 key {dist_bits, ~j}; dist>=0 so float-bit order == value order
    const int par = it & 1;
    if (win) {
      const unsigned wj = (unsigned)(tid + (bi << 8));
      sm->slotK[par][w] = ((u64)__float_as_uint(bv) << 32) | (u64)(~wj);
    }
    __syncthreads();

    // combine 4 keys (max = farthest; ties -> lowest j), then coords by index
    const uint4 s01 = *reinterpret_cast<const uint4*>(&sm->slotK[par][0]);
    const uint4 s23 = *reinterpret_cast<const uint4*>(&sm->slotK[par][2]);
    const u64 K0 = ((u64)s01.y << 32) | s01.x;
    const u64 K1 = ((u64)s01.w << 32) | s01.z;
    const u64 K2 = ((u64)s23.y << 32) | s23.x;
    const u64 K3 = ((u64)s23.w << 32) | s23.z;
    const u64 Ka = K0 > K1 ? K0 : K1;
    const u64 Kb = K2 > K3 ? K2 : K3;
    const u64 KW = Ka > Kb ? Ka : Kb;
    const unsigned wj = ~(unsigned)(KW & 0xffffffffu);
    const float4 c = sm->P4[wj];        // broadcast ds_read_b128
    sx = c.x; sy = c.y; sz = c.z;

    if (tid == 0) { selOut[3*it] = sx; selOut[3*it+1] = sy; selOut[3*it+2] = sz; }

    // distance update + per-lane argmax scan
    bv = -1.0f; bi = 0;
#pragma unroll
    for (int i = 0; i < R; i++) {
      const float dx = px[i]-sx, dy = py[i]-sy, dz = pz[i]-sz;
      const float d = __fadd_rn(__fadd_rn(__fmul_rn(dx,dx), __fmul_rn(dy,dy)), __fmul_rn(dz,dz));
      const float mv = fminf(mind[i], d);
      mind[i] = mv;
      if (mv > bv) { bv = mv; bi = i; }
    }
  }
}

// moments of a selected set in LDS (wave 0 only), stored TRANSPOSED: momT[k*S + b]
__device__ void mom_from_sel(const float* __restrict__ sel, int M, float* __restrict__ momT,
                             int S, int b, int lane) {
  float m0=0.f,m1=0.f,m2=0.f,m3=0.f,m4=0.f,m5=0.f,m6=0.f,m7=0.f,m8=0.f;
  for (int k = lane; k < M; k += 64) {
    const float x = sel[3*k], y = sel[3*k+1], z = sel[3*k+2];
    m0 += x; m1 += y; m2 += z;
    m3 = fmaf(x,x,m3); m4 = fmaf(y,y,m4); m5 = fmaf(z,z,m5);
    m6 = fmaf(x,y,m6); m7 = fmaf(x,z,m7); m8 = fmaf(y,z,m8);
  }
#pragma unroll
  for (int off = 32; off; off >>= 1) {
    m0 += __shfl_xor(m0, off); m1 += __shfl_xor(m1, off); m2 += __shfl_xor(m2, off);
    m3 += __shfl_xor(m3, off); m4 += __shfl_xor(m4, off); m5 += __shfl_xor(m5, off);
    m6 += __shfl_xor(m6, off); m7 += __shfl_xor(m7, off); m8 += __shfl_xor(m8, off);
  }
  if (lane == 0) {
    momT[0*S+b]=m0; momT[1*S+b]=m1; momT[2*S+b]=m2; momT[3*S+b]=m3; momT[4*S+b]=m4;
    momT[5*S+b]=m5; momT[6*S+b]=m6; momT[7*S+b]=m7; momT[8*S+b]=m8;
  }
}

// FPS chain: level-0 FPS then level-1 FPS on the selected set (still in LDS)
__device__ void fps_chain(const float* __restrict__ pts, float* __restrict__ pts1,
                          float* __restrict__ pts2, float* __restrict__ momT1,
                          float* __restrict__ momT2, FpsSm* sm) {
  const int b = blockIdx.x, tid = threadIdx.x, lane = tid & 63, w = tid >> 6;
  __builtin_amdgcn_s_setprio(1);

  fps_phase<2048>(pts + (size_t)b * 2048 * 3, sm->sel1, sm);
  __syncthreads();                       // sel1 complete
  {
    float* o = pts1 + (size_t)b * 1024 * 3;
#pragma unroll 4
    for (int e = tid; e < 3 * 1024; e += 256) o[e] = sm->sel1[e];
    if (w == 0) mom_from_sel(sm->sel1, 1024, momT1, 64, b, lane);
  }
  __syncthreads();

  fps_phase<1024>(sm->sel1, sm->sel2, sm);
  __syncthreads();                       // sel2 complete
  {
    float* o = pts2 + (size_t)b * 512 * 3;
#pragma unroll 4
    for (int e = tid; e < 3 * 512; e += 256) o[e] = sm->sel2[e];
    if (w == 0) mom_from_sel(sm->sel2, 512, momT2, 64, b, lane);
  }
  __builtin_amdgcn_s_setprio(0);
}

// ---------------- feature pass with inline BN1-fold (fin1) from transposed moments ----------------
template<int NPTS, int S>
__device__ void featB_body(const float* __restrict__ pts, const float* __restrict__ momT,
                           float Pinv, const float* __restrict__ w1lv,
                           const float* __restrict__ g1lv, const float* __restrict__ be1lv,
                           const float* __restrict__ w2lv, float* __restrict__ partialsB,
                           int fbid, FeatSm* sm) {
  const int tid  = threadIdx.x;
  const int lane = tid & 63;
  const int w    = tid >> 6;
  constexpr int BPB = NPTS / 256;
  const int b = fbid / BPB;
  const size_t pbase = (size_t)b * NPTS + (size_t)(fbid % BPB) * 256;

  // wave 0: fold BN1 into weights (9 DPP wave-sums over moment partials)
  if (w == 0) {
    float Mk[9];
#pragma unroll
    for (int k = 0; k < 9; k++) {
      float v = momT[k*S + lane];
      if (S == 128) v += momT[k*S + 64 + lane];
      Mk[k] = wave_sum_f32(v);
    }
    const int t = lane;
    const float w0 = w1lv[t], w1_ = w1lv[64 + t], w2_ = w1lv[128 + t];
    const float mean = (w0*Mk[0] + w1_*Mk[1] + w2_*Mk[2]) * Pinv;
    const float ey2  = (w0*w0*Mk[3] + w1_*w1_*Mk[4] + w2_*w2_*Mk[5]
                      + 2.f*(w0*w1_*Mk[6] + w0*w2_*Mk[7] + w1_*w2_*Mk[8])) * Pinv;
    const float var  = fmaxf(ey2 - mean*mean, 0.f);
    const float a    = g1lv[t] * rsqrtf(var + BN_EPS);
    float4 r; r.x = a*w0; r.y = a*w1_; r.z = a*w2_; r.w = fmaf(-a, mean, be1lv[t]);
    *reinterpret_cast<float4*>(&sm->W1s[t*4]) = r;
  }
  __syncthreads();

  float wA[64], wB[64];
#pragma unroll
  for (int k = 0; k < 64; k++) { wA[k] = w2lv[k*128 + lane]; wB[k] = w2lv[k*128 + 64 + lane]; }

  float sA=0.f, qA=0.f, sB=0.f, qB=0.f;
  float mxA=-1e30f, mnA=1e30f, mxB=-1e30f, mnB=1e30f;

  for (int r = 0; r < 2; r++) {
    __syncthreads();
    if (tid < 128) {
      const float* pp = pts + (pbase + (size_t)r*128 + tid) * 3;
      const float x = pp[0], y = pp[1], z = pp[2];
#pragma unroll
      for (int k = 0; k < 64; k += 4) {
        float4 hv;
        { const float4 wf = *reinterpret_cast<const float4*>(&sm->W1s[4*(k  )]);
          hv.x = fmaxf(0.f, fmaf(x,wf.x, fmaf(y,wf.y, fmaf(z,wf.z, wf.w)))); }
        { const float4 wf = *reinterpret_cast<const float4*>(&sm->W1s[4*(k+1)]);
          hv.y = fmaxf(0.f, fmaf(x,wf.x, fmaf(y,wf.y, fmaf(z,wf.z, wf.w)))); }
        { const float4 wf = *reinterpret_cast<const float4*>(&sm->W1s[4*(k+2)]);
          hv.z = fmaxf(0.f, fmaf(x,wf.x, fmaf(y,wf.y, fmaf(z,wf.z, wf.w)))); }
        { const float4 wf = *reinterpret_cast<const float4*>(&sm->W1s[4*(k+3)]);
          hv.w = fmaxf(0.f, fmaf(x,wf.x, fmaf(y,wf.y, fmaf(z,wf.z, wf.w)))); }
        *reinterpret_cast<float4*>(&sm->h1s[tid][k]) = hv;
      }
    }
    __syncthreads();
    const int row0 = w * 32;
    for (int p = row0; p < row0 + 32; ++p) {
      float ya = 0.f, yb = 0.f;
#pragma unroll
      for (int k = 0; k < 64; k += 4) {
        const float4 hv = *reinterpret_cast<const float4*>(&sm->h1s[p][k]);
        ya = fmaf(hv.x, wA[k  ], ya);  yb = fmaf(hv.x, wB[k  ], yb);
        ya = fmaf(hv.y, wA[k+1], ya);  yb = fmaf(hv.y, wB[k+1], yb);
        ya = fmaf(hv.z, wA[k+2], ya);  yb = fmaf(hv.z, wB[k+2], yb);
        ya = fmaf(hv.w, wA[k+3], ya);  yb = fmaf(hv.w, wB[k+3], yb);
      }
      sA += ya; qA = fmaf(ya,ya,qA); mxA = fmaxf(mxA,ya); mnA = fminf(mnA,ya);
      sB += yb; qB = fmaf(yb,yb,qB); mxB = fmaxf(mxB,yb); mnB = fminf(mnB,yb);
    }
  }

  float4* st = reinterpret_cast<float4*>(&sm->stat[w][lane][0]);
  st[0] = make_float4(sA,qA,mxA,mnA);
  st[1] = make_float4(sB,qB,mxB,mnB);
  __syncthreads();
  if (w == 0) {
    float4 aA = *reinterpret_cast<float4*>(&sm->stat[0][lane][0]);
    float4 aB = *reinterpret_cast<float4*>(&sm->stat[0][lane][4]);
#pragma unroll
    for (int q = 1; q < 4; q++) {
      const float4 cA = *reinterpret_cast<float4*>(&sm->stat[q][lane][0]);
      const float4 cB = *reinterpret_cast<float4*>(&sm->stat[q][lane][4]);
      aA.x += cA.x; aA.y += cA.y; aA.z = fmaxf(aA.z,cA.z); aA.w = fminf(aA.w,cA.w);
      aB.x += cB.x; aB.y += cB.y; aB.z = fmaxf(aB.z,cB.z); aB.w = fminf(aB.w,cB.w);
    }
    float* pb = partialsB + (size_t)fbid * 512;
    pb[0*128 +      lane] = aA.x; pb[1*128 +      lane] = aA.y;
    pb[2*128 +      lane] = aA.z; pb[3*128 +      lane] = aA.w;
    pb[0*128 + 64 + lane] = aB.x; pb[1*128 + 64 + lane] = aB.y;
    pb[2*128 + 64 + lane] = aB.z; pb[3*128 + 64 + lane] = aB.w;
  }
}

// ---------------- fused BN2-coeffs + maxpool(relu(BN2(y2))) per batch ----------------
__device__ void f2ab_body(const float* __restrict__ partB, int nb, int bpb, float Pinv,
    const float* __restrict__ g2, const float* __restrict__ be2,
    float* __restrict__ out, int lv, int b) {
  const int ch = threadIdx.x;   // 128 active threads
  float s = 0.f, q = 0.f;
  for (int i = 0; i < nb; i++) {
    s += partB[(size_t)i*512 + ch];
    q += partB[(size_t)i*512 + 128 + ch];
  }
  const float mean = s * Pinv;
  const float var  = fmaxf(q * Pinv - mean*mean, 0.f);
  const float a    = g2[ch] * rsqrtf(var + BN_EPS);
  const float c    = fmaf(-a, mean, be2[ch]);
  const float* pb = partB + (size_t)b * bpb * 512;
  float mx = -1e30f, mn = 1e30f;
  for (int i = 0; i < bpb; i++) {
    mx = fmaxf(mx, pb[(size_t)i*512 + 256 + ch]);
    mn = fminf(mn, pb[(size_t)i*512 + 384 + ch]);
  }
  const float v = (a >= 0.f) ? mx : mn;
  out[b*384 + lv*128 + ch] = fmaxf(0.f, fmaf(a, v, c));
}

// ---------------- level-0 moment reduction (transposed output) ----------------
__global__ __launch_bounds__(256) void mom0_kernel(const float* __restrict__ pts,
                                                   float* __restrict__ mpT) {
  __shared__ float red[256];
  const int tid = threadIdx.x;
  float acc[9] = {0,0,0,0,0,0,0,0,0};
#pragma unroll
  for (int i = 0; i < 4; i++) {
    const size_t j = (size_t)blockIdx.x * 1024 + (size_t)i * 256 + tid;
    const float x = pts[3*j], y = pts[3*j+1], z = pts[3*j+2];
    acc[0]+=x; acc[1]+=y; acc[2]+=z;
    acc[3]=fmaf(x,x,acc[3]); acc[4]=fmaf(y,y,acc[4]); acc[5]=fmaf(z,z,acc[5]);
    acc[6]=fmaf(x,y,acc[6]); acc[7]=fmaf(x,z,acc[7]); acc[8]=fmaf(y,z,acc[8]);
  }
  for (int k = 0; k < 9; k++) {
    red[tid] = acc[k]; __syncthreads();
    for (int s = 128; s > 0; s >>= 1) { if (tid < s) red[tid] += red[tid+s]; __syncthreads(); }
    if (tid == 0) mpT[k*128 + blockIdx.x] = red[0];
    __syncthreads();
  }
}

// ---------------- K_A: blocks 0..63 = fused FPS0+FPS1, rest = feat level-0 ----------------
__global__ __launch_bounds__(256, 2) void kA_kernel(const float* __restrict__ pts,
    const float* __restrict__ momT0, const float* __restrict__ w1,
    const float* __restrict__ g1, const float* __restrict__ be1, const float* __restrict__ w2,
    float* __restrict__ partB0, float* __restrict__ pts1, float* __restrict__ pts2,
    float* __restrict__ momT1, float* __restrict__ momT2) {
  __shared__ SMem sm;
  if (blockIdx.x < 64) { fps_chain(pts, pts1, pts2, momT1, momT2, &sm.fps); return; }
  featB_body<2048, 128>(pts, momT0, 1.f/131072.f, w1, g1, be1, w2, partB0,
                        (int)blockIdx.x - 64, &sm.feat);
}

// ---------------- K_B: feat1 (256) + feat2 (128) + f2ab lv0 (64) ----------------
__global__ __launch_bounds__(256, 2) void kB_kernel(const float* __restrict__ pts1,
    const float* __restrict__ pts2, const float* __restrict__ momT1,
    const float* __restrict__ momT2, const float* __restrict__ w1,
    const float* __restrict__ g1, const float* __restrict__ be1, const float* __restrict__ w2,
    const float* __restrict__ g2, const float* __restrict__ be2,
    float* __restrict__ partB1, float* __restrict__ partB2,
    const float* __restrict__ partB0, float* __restrict__ out) {
  __shared__ SMem sm;
  if (blockIdx.x < 256) {
    featB_body<1024, 64>(pts1, momT1, 1.f/65536.f, w1 + 192, g1 + 64, be1 + 64,
                         w2 + 8192, partB1, (int)blockIdx.x, &sm.feat);
  } else if (blockIdx.x < 384) {
    featB_body<512, 64>(pts2, momT2, 1.f/32768.f, w1 + 384, g1 + 128, be1 + 128,
                        w2 + 16384, partB2, (int)blockIdx.x - 256, &sm.feat);
  } else if (threadIdx.x < 128) {
    f2ab_body(partB0, 512, 8, 1.f/131072.f, g2, be2, out, 0, (int)blockIdx.x - 384);
  }
}

// ---------------- postF: f2ab lv1 (64 blocks) + lv2 (64 blocks) ----------------
__global__ __launch_bounds__(128) void postF_kernel(const float* __restrict__ partB1,
    const float* __restrict__ partB2, const float* __restrict__ g2,
    const float* __restrict__ be2, float* __restrict__ out) {
  if (blockIdx.x < 64) f2ab_body(partB1, 256, 4, 1.f/65536.f, g2 + 128, be2 + 128, out, 1, (int)blockIdx.x);
  else                 f2ab_body(partB2, 128, 2, 1.f/32768.f, g2 + 256, be2 + 256, out, 2, (int)blockIdx.x - 64);
}

// ---------------- host launch ----------------
extern "C" void kernel_launch(void* const* d_in, const int* in_sizes, int n_in,
                              void* d_out, int out_size, void* d_ws, size_t ws_size,
                              hipStream_t stream) {
  const float* pts = (const float*)d_in[0];
  const float* w1  = (const float*)d_in[1];
  const float* g1  = (const float*)d_in[3];
  const float* be1 = (const float*)d_in[4];
  const float* w2  = (const float*)d_in[5];
  const float* g2  = (const float*)d_in[7];
  const float* be2 = (const float*)d_in[8];
  float* out = (float*)d_out;
  float* wsf = (float*)d_ws;

  float* pts1   = wsf;                  // 196608
  float* pts2   = pts1   + 196608;      //  98304
  float* momT0  = pts2   + 98304;       //    1152 (9 x 128, transposed)
  float* momT1  = momT0  + 1152;        //     576 (9 x 64)
  float* momT2  = momT1  + 576;         //     576
  float* partB0 = momT2  + 576;         //  262144 (512 x 512)
  float* partB1 = partB0 + 262144;      //  131072 (256 x 512)
  float* partB2 = partB1 + 131072;      //   65536 (128 x 512)

  mom0_kernel<<<128, 256, 0, stream>>>(pts, momT0);
  kA_kernel<<<64 + 512, 256, 0, stream>>>(pts, momT0, w1, g1, be1, w2,
                                          partB0, pts1, pts2, momT1, momT2);
  kB_kernel<<<256 + 128 + 64, 256, 0, stream>>>(pts1, pts2, momT1, momT2, w1, g1, be1, w2,
                                                g2, be2, partB1, partB2, partB0, out);
  postF_kernel<<<128, 128, 0, stream>>>(partB1, partB2, g2, be2, out);
}